// Round 10
// baseline (143.502 us; speedup 1.0000x reference)
//
#include <hip/hip_runtime.h>
#include <hip/hip_fp8.h>
#include <stdint.h>

#define D_DIM 512
#define B_ROWS 1024
#define C_ROWS 32768
#define NBLK (C_ROWS / 128)   // 256 n-blocks

typedef __attribute__((ext_vector_type(4))) float floatx4;
typedef __attribute__((ext_vector_type(4))) int intx4;
typedef __attribute__((ext_vector_type(8))) int intx8;

#define GLOBAL_AS __attribute__((address_space(1)))
#define LDS_AS __attribute__((address_space(3)))

__device__ inline void async_copy16(const unsigned char* g, unsigned char* l) {
    __builtin_amdgcn_global_load_lds((const GLOBAL_AS void*)g, (LDS_AS void*)l, 16, 0, 0);
}

// OCP e4m3 encode/decode via the HIP type (HW cvt on gfx950)
__device__ inline unsigned char f2fp8(float x) {
    __hip_fp8_e4m3 t(x);
    return t.__x;
}
__device__ inline float fp8tof(unsigned char v) {
    __hip_fp8_e4m3 t;
    t.__x = v;
    return (float)t;
}

// Fragment layout v2 (K=128 MFMA, BOTH matrices). Region R(t16, kc) = 2048 B
// at offset t16*8192 + kc*2048 holds rows [t16*16, +16), k-bytes
// [kc*128, +128). Within a region:
//   byte h*1024 + (quad*16 + fr)*16 + b  (h in {0,1}, b in [0,16))
//   = row[t16*16 + fr], k-byte kc*128 + quad*32 + h*16 + b.
// MFMA lane (fr = lane&15, quad = lane>>4) reads its 32 k-bytes as two
// contiguous 16-B pieces at region + lane*16 and +1024 + lane*16 — coalesced
// global dwordx4 pairs (A, register pipeline) / conflict-free stride-16
// ds_read_b128 pairs (B, LDS), and staging is a pure linear copy.

// Normalize rows of BOTH inputs to norm 3, emit fp8 e4m3 in layout v2.
// One wave per row; lane covers k = lane*8..+8. Block 0 inits acc/ticket.
__global__ void norm_rows_kernel(const float* __restrict__ prox,
                                 const float* __restrict__ emb,
                                 unsigned char* __restrict__ Pq,
                                 unsigned char* __restrict__ Aq,
                                 float* __restrict__ acc,
                                 unsigned* __restrict__ ticket) {
    if (blockIdx.x == 0 && threadIdx.x == 0) { *acc = 0.f; *ticket = 0u; }
    const int wid = threadIdx.x >> 6;
    const int lane = threadIdx.x & 63;
    int row = blockIdx.x * 4 + wid;
    const float* src;
    unsigned char* dst;
    if (row < C_ROWS) {
        src = prox; dst = Pq;
    } else {
        row -= C_ROWS;
        src = emb; dst = Aq;
    }

    const float4* p = (const float4*)(src + (size_t)row * D_DIM + lane * 8);
    float4 v0 = p[0];
    float4 v1 = p[1];
    float ss = v0.x * v0.x + v0.y * v0.y + v0.z * v0.z + v0.w * v0.w +
               v1.x * v1.x + v1.y * v1.y + v1.z * v1.z + v1.w * v1.w;
#pragma unroll
    for (int off = 1; off < 64; off <<= 1) ss += __shfl_xor(ss, off);
    // norms are ~2.8..23 here, far above the 1e-12 eps in the reference
    const float s = 3.0f * rsqrtf(ss);

    unsigned char q[8];
    q[0] = f2fp8(v0.x * s); q[1] = f2fp8(v0.y * s);
    q[2] = f2fp8(v0.z * s); q[3] = f2fp8(v0.w * s);
    q[4] = f2fp8(v1.x * s); q[5] = f2fp8(v1.y * s);
    q[6] = f2fp8(v1.z * s); q[7] = f2fp8(v1.w * s);
    uint2 packed;
    packed.x = (unsigned)q[0] | ((unsigned)q[1] << 8) |
               ((unsigned)q[2] << 16) | ((unsigned)q[3] << 24);
    packed.y = (unsigned)q[4] | ((unsigned)q[5] << 8) |
               ((unsigned)q[6] << 16) | ((unsigned)q[7] << 24);

    // k = lane*8: kc = lane>>4, quad = (lane>>2)&3, h = (lane>>1)&1, b0 = (lane&1)*8
    const size_t addr = (size_t)(row >> 4) * 8192 + (lane >> 4) * 2048 +
                        ((lane >> 1) & 1) * 1024 + ((lane >> 2) & 3) * 256 +
                        (row & 15) * 16 + (lane & 1) * 8;
    *(uint2*)(dst + addr) = packed;
}

// 128x128 tile GEMM over K=512 using MX-scaled fp8 MFMA (16x16x128, unity
// e8m0 scales). Depth-2 pipeline with ONE barrier per BK=128 chunk (4 total):
//  - B: LDS double-buffer (2x16 KB, same 33 KB footprint as single-buffered
//    round 9 -> occupancy unchanged); prefetch for chunk c+1 issued right
//    after barrier c, drained at barrier c+1 (a full compute phase of cover).
//  - A: register pipeline (32 B/lane/chunk as two coalesced dwordx4) -- no
//    LDS, no barrier interaction; A is L2-hot (512 KB total).
// Epilogue: exp(2*S) row-sums -> part[nblk][m] (coalesced 512 B).
__global__ void __launch_bounds__(256, 3)
gemm_lse_kernel(const unsigned char* __restrict__ Aq,
                const unsigned char* __restrict__ Bq,
                float* __restrict__ part) {
    __shared__ __align__(16) unsigned char sB[2][16384];  // 2 x (8 t16 x 2048 B)
    __shared__ float red[128];

    const int tid = threadIdx.x;
    const int wid = tid >> 6;
    const int lane = tid & 63;
    const int n0t = blockIdx.x * 8;   // n base in t16 units (n-fastest grid)
    const int m0t = blockIdx.y * 8;   // m base in t16 units

    if (tid < 128) red[tid] = 0.f;

    // 2x2 wave arrangement, each wave owns 64x64 via 4x4 MFMA 16x16x128 tiles
    const int wmt = (wid >> 1) * 4;
    const int wnt = (wid & 1) * 4;
    const int wm = wmt * 16;
    const int fr = lane & 15;
    const int quad = lane >> 4;

    // A register-operand base: fragment (t, c) at Abase + t*8192 + c*2048 (+1024)
    const unsigned char* Abase = Aq + (size_t)(m0t + wmt) * 8192 + lane * 16;

    floatx4 acc[4][4];
    const floatx4 zero = {0.f, 0.f, 0.f, 0.f};
#pragma unroll
    for (int i = 0; i < 4; ++i)
#pragma unroll
        for (int j = 0; j < 4; ++j) acc[i][j] = zero;

    // B staging for chunk c into dbuf d: wave wid covers t16_local {2wid, 2wid+1}
    // x half {0,1} -- 4 linear 1024-B copies per wave.
#define STAGE_B(d, c)                                                         \
    do {                                                                      \
        _Pragma("unroll")                                                     \
        for (int j = 0; j < 4; ++j) {                                         \
            const int tl = wid * 2 + (j >> 1);                                \
            const int half = j & 1;                                           \
            async_copy16(Bq + (size_t)(n0t + tl) * 8192 + (c) * 2048 +        \
                             half * 1024 + lane * 16,                         \
                         &sB[d][tl * 2048 + half * 1024 + lane * 16]);        \
        }                                                                     \
    } while (0)

    // A register load for chunk c into slot d
    intx8 a[2][4];
#define LOAD_A(d, c)                                                          \
    do {                                                                      \
        _Pragma("unroll")                                                     \
        for (int t = 0; t < 4; ++t) {                                         \
            intx4 lo = *(const intx4*)(Abase + t * 8192 + (c) * 2048);        \
            intx4 hi = *(const intx4*)(Abase + t * 8192 + (c) * 2048 + 1024); \
            a[d][t] = __builtin_shufflevector(lo, hi, 0, 1, 2, 3, 4, 5, 6, 7);\
        }                                                                     \
    } while (0)

    STAGE_B(0, 0);  // prologue
    LOAD_A(0, 0);

#pragma unroll
    for (int c = 0; c < 4; ++c) {
        const int cur = c & 1;
        // Drains vmcnt(0): B(c) resident in sB[cur], a[cur] loaded. The other
        // buffer's last readers finished before the PREVIOUS barrier, so the
        // prefetch below can't race them.
        __syncthreads();
        if (c < 3) {
            STAGE_B(cur ^ 1, c + 1);  // in flight for the whole compute phase
            LOAD_A(cur ^ 1, c + 1);
        }
#pragma unroll
        for (int tj = 0; tj < 4; ++tj) {
            const int ob = (wnt + tj) * 2048 + lane * 16;
            intx4 blo = *(const intx4*)&sB[cur][ob];
            intx4 bhi = *(const intx4*)&sB[cur][ob + 1024];
            intx8 b8 = __builtin_shufflevector(blo, bhi, 0, 1, 2, 3, 4, 5, 6, 7);
#pragma unroll
            for (int ti = 0; ti < 4; ++ti)
                acc[ti][tj] = __builtin_amdgcn_mfma_scale_f32_16x16x128_f8f6f4(
                    a[cur][ti], b8, acc[ti][tj],
                    0 /*cbsz: A=fp8 e4m3*/, 0 /*blgp: B=fp8 e4m3*/,
                    0, 0x7F /*scale A = 2^0*/, 0, 0x7F /*scale B = 2^0*/);
        }
    }
#undef STAGE_B
#undef LOAD_A

    // Epilogue: red[m_local] += sum over this block's 128 cols of exp(2*S).
    // C/D layout: col = lane&15, row = quad*4 + reg (shape-determined)
#pragma unroll
    for (int ti = 0; ti < 4; ++ti) {
        float rs[4] = {0.f, 0.f, 0.f, 0.f};
#pragma unroll
        for (int tj = 0; tj < 4; ++tj)
#pragma unroll
            for (int r = 0; r < 4; ++r)
                rs[r] += __expf(2.0f * acc[ti][tj][r]);
        // sum across the 16 col-lanes (bits 0..3 of lane)
#pragma unroll
        for (int r = 0; r < 4; ++r) {
            rs[r] += __shfl_xor(rs[r], 1);
            rs[r] += __shfl_xor(rs[r], 2);
            rs[r] += __shfl_xor(rs[r], 4);
            rs[r] += __shfl_xor(rs[r], 8);
        }
        if (fr == 0) {
#pragma unroll
            for (int r = 0; r < 4; ++r)
                atomicAdd(&red[wm + ti * 16 + quad * 4 + r], rs[r]);  // LDS atomic
        }
    }
    __syncthreads();
    // part layout [nblk][m]: 128 consecutive floats -> fully coalesced 512 B
    if (tid < 128)
        part[(size_t)blockIdx.x * B_ROWS + m0t * 16 + tid] = red[tid];
}

// Fused: sum 256 partials/row, positive dot (layout-v2 reads), row loss,
// grid combine via ticket; last block writes the mean.
__global__ void finalize_kernel(const float* __restrict__ part,
                                const unsigned char* __restrict__ Aq,
                                const unsigned char* __restrict__ Pq,
                                const int* __restrict__ labels,
                                float* __restrict__ acc,
                                unsigned* __restrict__ ticket,
                                float* __restrict__ out) {
    __shared__ float r4s[4];
    const int tid = threadIdx.x;
    const int wid = tid >> 6;
    const int lane = tid & 63;
    const int b = blockIdx.x * 4 + wid;   // grid = 256 blocks, 4 rows each

    // 256 partials for row b, strided by B_ROWS (L2-resident 1 MB)
    float s = 0.f;
#pragma unroll
    for (int k = 0; k < 4; ++k)
        s += part[(size_t)(lane * 4 + k) * B_ROWS + b];

    // positive dot from the same fp8 data the GEMM consumed (layout v2)
    const int l = labels[b];
    const size_t ua_addr = (size_t)(b >> 4) * 8192 + (lane >> 4) * 2048 +
                           ((lane >> 1) & 1) * 1024 + ((lane >> 2) & 3) * 256 +
                           (b & 15) * 16 + (lane & 1) * 8;
    const size_t ub_addr = (size_t)(l >> 4) * 8192 + (lane >> 4) * 2048 +
                           ((lane >> 1) & 1) * 1024 + ((lane >> 2) & 3) * 256 +
                           (l & 15) * 16 + (lane & 1) * 8;
    uint2 ua = *(const uint2*)(Aq + ua_addr);
    uint2 ub = *(const uint2*)(Pq + ub_addr);
    const unsigned char* au = (const unsigned char*)&ua;
    const unsigned char* bu = (const unsigned char*)&ub;
    float d = 0.f;
#pragma unroll
    for (int j = 0; j < 8; ++j) d += fp8tof(au[j]) * fp8tof(bu[j]);
#pragma unroll
    for (int off = 1; off < 64; off <<= 1) {
        s += __shfl_xor(s, off);
        d += __shfl_xor(d, off);
    }

    if (lane == 0) {
        float p2 = 2.0f * d;
        r4s[wid] = logf(s - __expf(p2)) - p2;  // mask positive class
    }
    __syncthreads();
    if (tid == 0) {
        float bl = r4s[0] + r4s[1] + r4s[2] + r4s[3];
        atomicAdd(acc, bl);
        __threadfence();
        unsigned t = atomicAdd(ticket, 1u);
        if (t == 255u) {  // last block: all 256 contributions are in
            float total = atomicAdd(acc, 0.f);  // coherent device-scope read
            out[0] = total / (float)B_ROWS;
        }
    }
}

extern "C" void kernel_launch(void* const* d_in, const int* in_sizes, int n_in,
                              void* d_out, int out_size, void* d_ws, size_t ws_size,
                              hipStream_t stream) {
    const float* emb = (const float*)d_in[0];    // [1024, 512]
    const float* prox = (const float*)d_in[1];   // [32768, 512]
    const int* labels = (const int*)d_in[2];     // [1024]
    float* out = (float*)d_out;

    char* ws = (char*)d_ws;
    unsigned char* Pq = (unsigned char*)ws;                            // 16 MB
    unsigned char* Aq = Pq + (size_t)C_ROWS * D_DIM;                   // 512 KB
    float* part = (float*)(Aq + (size_t)B_ROWS * D_DIM);               // 1 MB
    float* acc = part + (size_t)NBLK * B_ROWS;
    unsigned* ticket = (unsigned*)(acc + 1);

    norm_rows_kernel<<<(C_ROWS + B_ROWS) / 4, 256, 0, stream>>>(
        prox, emb, Pq, Aq, acc, ticket);
    gemm_lse_kernel<<<dim3(NBLK, B_ROWS / 128), 256, 0, stream>>>(Aq, Pq, part);
    finalize_kernel<<<B_ROWS / 4, 256, 0, stream>>>(
        part, Aq, Pq, labels, acc, ticket, out);
}

// Round 11
// 135.945 us; speedup vs baseline: 1.0556x; 1.0556x over previous
//
#include <hip/hip_runtime.h>
#include <hip/hip_fp8.h>
#include <stdint.h>

#define D_DIM 512
#define B_ROWS 1024
#define C_ROWS 32768
#define NBLK (C_ROWS / 128)   // 256 n-blocks

typedef __attribute__((ext_vector_type(4))) float floatx4;
typedef __attribute__((ext_vector_type(4))) int intx4;
typedef __attribute__((ext_vector_type(8))) int intx8;

#define GLOBAL_AS __attribute__((address_space(1)))
#define LDS_AS __attribute__((address_space(3)))

__device__ inline void async_copy16(const unsigned char* g, unsigned char* l) {
    __builtin_amdgcn_global_load_lds((const GLOBAL_AS void*)g, (LDS_AS void*)l, 16, 0, 0);
}

// OCP e4m3 encode/decode via the HIP type (HW cvt on gfx950)
__device__ inline unsigned char f2fp8(float x) {
    __hip_fp8_e4m3 t(x);
    return t.__x;
}
__device__ inline float fp8tof(unsigned char v) {
    __hip_fp8_e4m3 t;
    t.__x = v;
    return (float)t;
}

// Fragment layout v2 (K=128 MFMA, BOTH matrices). Region R(t16, kc) = 2048 B
// at offset t16*8192 + kc*2048 holds rows [t16*16, +16), k-bytes
// [kc*128, +128). Within a region:
//   byte h*1024 + (quad*16 + fr)*16 + b  (h in {0,1}, b in [0,16))
//   = row[t16*16 + fr], k-byte kc*128 + quad*32 + h*16 + b.
// MFMA lane (fr = lane&15, quad = lane>>4) reads its 32 k-bytes as two
// contiguous stride-16 ds_read_b128 at region + lane*16 and +1024 + lane*16
// (zero bank conflicts), and staging is a pure linear global_load_lds copy.

// Normalize rows of BOTH inputs to norm 3, emit fp8 e4m3 in layout v2.
// One wave per row; lane covers k = lane*8..+8. Block 0 inits acc/ticket.
__global__ void norm_rows_kernel(const float* __restrict__ prox,
                                 const float* __restrict__ emb,
                                 unsigned char* __restrict__ Pq,
                                 unsigned char* __restrict__ Aq,
                                 float* __restrict__ acc,
                                 unsigned* __restrict__ ticket) {
    if (blockIdx.x == 0 && threadIdx.x == 0) { *acc = 0.f; *ticket = 0u; }
    const int wid = threadIdx.x >> 6;
    const int lane = threadIdx.x & 63;
    int row = blockIdx.x * 4 + wid;
    const float* src;
    unsigned char* dst;
    if (row < C_ROWS) {
        src = prox; dst = Pq;
    } else {
        row -= C_ROWS;
        src = emb; dst = Aq;
    }

    const float4* p = (const float4*)(src + (size_t)row * D_DIM + lane * 8);
    float4 v0 = p[0];
    float4 v1 = p[1];
    float ss = v0.x * v0.x + v0.y * v0.y + v0.z * v0.z + v0.w * v0.w +
               v1.x * v1.x + v1.y * v1.y + v1.z * v1.z + v1.w * v1.w;
#pragma unroll
    for (int off = 1; off < 64; off <<= 1) ss += __shfl_xor(ss, off);
    // norms are ~2.8..23 here, far above the 1e-12 eps in the reference
    const float s = 3.0f * rsqrtf(ss);

    unsigned char q[8];
    q[0] = f2fp8(v0.x * s); q[1] = f2fp8(v0.y * s);
    q[2] = f2fp8(v0.z * s); q[3] = f2fp8(v0.w * s);
    q[4] = f2fp8(v1.x * s); q[5] = f2fp8(v1.y * s);
    q[6] = f2fp8(v1.z * s); q[7] = f2fp8(v1.w * s);
    uint2 packed;
    packed.x = (unsigned)q[0] | ((unsigned)q[1] << 8) |
               ((unsigned)q[2] << 16) | ((unsigned)q[3] << 24);
    packed.y = (unsigned)q[4] | ((unsigned)q[5] << 8) |
               ((unsigned)q[6] << 16) | ((unsigned)q[7] << 24);

    // k = lane*8: kc = lane>>4, quad = (lane>>2)&3, h = (lane>>1)&1, b0 = (lane&1)*8
    const size_t addr = (size_t)(row >> 4) * 8192 + (lane >> 4) * 2048 +
                        ((lane >> 1) & 1) * 1024 + ((lane >> 2) & 3) * 256 +
                        (row & 15) * 16 + (lane & 1) * 8;
    *(uint2*)(dst + addr) = packed;
}

// 128x128 tile GEMM over K=512 using MX-scaled fp8 MFMA (16x16x128, unity
// e8m0 scales = pure fp8 matmul at 2x the non-scaled rate). BK=128, 4 chunks,
// both operands LDS-staged via linear global_load_lds from layout v2.
// Fragment reads: contiguous stride-16 ds_read_b128 pairs (zero conflicts).
// Single-buffered 2-barrier K-loop: R5/R10 (and m99/m100/m131-141) showed
// explicit pipelining regresses this structure from HIP source.
// Epilogue: exp(2*S) row-sums -> part[nblk][m] (coalesced 512 B).
__global__ void __launch_bounds__(256, 3)
gemm_lse_kernel(const unsigned char* __restrict__ Aq,
                const unsigned char* __restrict__ Bq,
                float* __restrict__ part) {
    __shared__ __align__(16) unsigned char sA[16384];  // 8 t16 x 2048 B
    __shared__ __align__(16) unsigned char sB[16384];
    __shared__ float red[128];

    const int tid = threadIdx.x;
    const int wid = tid >> 6;
    const int lane = tid & 63;
    const int n0t = blockIdx.x * 8;   // n base in t16 units (n-fastest grid)
    const int m0t = blockIdx.y * 8;   // m base in t16 units

    if (tid < 128) red[tid] = 0.f;

    // 2x2 wave arrangement, each wave owns 64x64 via 4x4 MFMA 16x16x128 tiles
    const int wmt = (wid >> 1) * 4;
    const int wnt = (wid & 1) * 4;
    const int wm = wmt * 16;
    const int fr = lane & 15;
    const int quad = lane >> 4;

    floatx4 acc[4][4];
    const floatx4 zero = {0.f, 0.f, 0.f, 0.f};
#pragma unroll
    for (int i = 0; i < 4; ++i)
#pragma unroll
        for (int j = 0; j < 4; ++j) acc[i][j] = zero;

    for (int c = 0; c < 4; ++c) {
        // stage chunk c: wave wid covers t16_local {2*wid, 2*wid+1}; each
        // region is 2048 B = 2 linear 1024-B copies. 8 calls per wave.
#pragma unroll
        for (int j = 0; j < 4; ++j) {
            const int tl = wid * 2 + (j >> 1);
            const int half = j & 1;
            const size_t goA = (size_t)(m0t + tl) * 8192 + c * 2048 + half * 1024;
            const size_t goB = (size_t)(n0t + tl) * 8192 + c * 2048 + half * 1024;
            const int lo = tl * 2048 + half * 1024 + lane * 16;
            async_copy16(Aq + goA + lane * 16, &sA[lo]);
            async_copy16(Bq + goB + lane * 16, &sB[lo]);
        }
        __syncthreads();  // drains vmcnt(0): chunk resident

        // fragments: lane's 32 k-bytes = two 16-B halves at LDS stride 1024
        intx8 a8[4], b8[4];
#pragma unroll
        for (int t = 0; t < 4; ++t) {
            const int oa = (wmt + t) * 2048 + lane * 16;
            const int ob = (wnt + t) * 2048 + lane * 16;
            intx4 alo = *(const intx4*)&sA[oa];
            intx4 ahi = *(const intx4*)&sA[oa + 1024];
            intx4 blo = *(const intx4*)&sB[ob];
            intx4 bhi = *(const intx4*)&sB[ob + 1024];
            a8[t] = __builtin_shufflevector(alo, ahi, 0, 1, 2, 3, 4, 5, 6, 7);
            b8[t] = __builtin_shufflevector(blo, bhi, 0, 1, 2, 3, 4, 5, 6, 7);
        }
#pragma unroll
        for (int ti = 0; ti < 4; ++ti)
#pragma unroll
            for (int tj = 0; tj < 4; ++tj)
                acc[ti][tj] = __builtin_amdgcn_mfma_scale_f32_16x16x128_f8f6f4(
                    a8[ti], b8[tj], acc[ti][tj],
                    0 /*cbsz: A=fp8 e4m3*/, 0 /*blgp: B=fp8 e4m3*/,
                    0, 0x7F /*scale A = 2^0*/, 0, 0x7F /*scale B = 2^0*/);
        // protect LDS before the next chunk's staging overwrites it; not
        // needed after the last chunk (epilogue has its own barrier).
        if (c < 3) __syncthreads();
    }

    // Epilogue: red[m_local] += sum over this block's 128 cols of exp(2*S).
    // C/D layout: col = lane&15, row = quad*4 + reg (shape-determined, m121-128)
#pragma unroll
    for (int ti = 0; ti < 4; ++ti) {
        float rs[4] = {0.f, 0.f, 0.f, 0.f};
#pragma unroll
        for (int tj = 0; tj < 4; ++tj)
#pragma unroll
            for (int r = 0; r < 4; ++r)
                rs[r] += __expf(2.0f * acc[ti][tj][r]);
        // sum across the 16 col-lanes (bits 0..3 of lane)
#pragma unroll
        for (int r = 0; r < 4; ++r) {
            rs[r] += __shfl_xor(rs[r], 1);
            rs[r] += __shfl_xor(rs[r], 2);
            rs[r] += __shfl_xor(rs[r], 4);
            rs[r] += __shfl_xor(rs[r], 8);
        }
        if (fr == 0) {
#pragma unroll
            for (int r = 0; r < 4; ++r)
                atomicAdd(&red[wm + ti * 16 + quad * 4 + r], rs[r]);  // LDS atomic
        }
    }
    __syncthreads();
    // part layout [nblk][m]: 128 consecutive floats -> fully coalesced 512 B
    if (tid < 128)
        part[(size_t)blockIdx.x * B_ROWS + m0t * 16 + tid] = red[tid];
}

// Fused: sum 256 partials/row, positive dot (layout-v2 reads), row loss,
// grid combine via ticket; last block writes the mean.
__global__ void finalize_kernel(const float* __restrict__ part,
                                const unsigned char* __restrict__ Aq,
                                const unsigned char* __restrict__ Pq,
                                const int* __restrict__ labels,
                                float* __restrict__ acc,
                                unsigned* __restrict__ ticket,
                                float* __restrict__ out) {
    __shared__ float r4s[4];
    const int tid = threadIdx.x;
    const int wid = tid >> 6;
    const int lane = tid & 63;
    const int b = blockIdx.x * 4 + wid;   // grid = 256 blocks, 4 rows each

    // 256 partials for row b, strided by B_ROWS (L2-resident 1 MB)
    float s = 0.f;
#pragma unroll
    for (int k = 0; k < 4; ++k)
        s += part[(size_t)(lane * 4 + k) * B_ROWS + b];

    // positive dot from the same fp8 data the GEMM consumed (layout v2)
    const int l = labels[b];
    const size_t ua_addr = (size_t)(b >> 4) * 8192 + (lane >> 4) * 2048 +
                           ((lane >> 1) & 1) * 1024 + ((lane >> 2) & 3) * 256 +
                           (b & 15) * 16 + (lane & 1) * 8;
    const size_t ub_addr = (size_t)(l >> 4) * 8192 + (lane >> 4) * 2048 +
                           ((lane >> 1) & 1) * 1024 + ((lane >> 2) & 3) * 256 +
                           (l & 15) * 16 + (lane & 1) * 8;
    uint2 ua = *(const uint2*)(Aq + ua_addr);
    uint2 ub = *(const uint2*)(Pq + ub_addr);
    const unsigned char* au = (const unsigned char*)&ua;
    const unsigned char* bu = (const unsigned char*)&ub;
    float d = 0.f;
#pragma unroll
    for (int j = 0; j < 8; ++j) d += fp8tof(au[j]) * fp8tof(bu[j]);
#pragma unroll
    for (int off = 1; off < 64; off <<= 1) {
        s += __shfl_xor(s, off);
        d += __shfl_xor(d, off);
    }

    if (lane == 0) {
        float p2 = 2.0f * d;
        r4s[wid] = logf(s - __expf(p2)) - p2;  // mask positive class
    }
    __syncthreads();
    if (tid == 0) {
        float bl = r4s[0] + r4s[1] + r4s[2] + r4s[3];
        atomicAdd(acc, bl);
        __threadfence();
        unsigned t = atomicAdd(ticket, 1u);
        if (t == 255u) {  // last block: all 256 contributions are in
            float total = atomicAdd(acc, 0.f);  // coherent device-scope read
            out[0] = total / (float)B_ROWS;
        }
    }
}

extern "C" void kernel_launch(void* const* d_in, const int* in_sizes, int n_in,
                              void* d_out, int out_size, void* d_ws, size_t ws_size,
                              hipStream_t stream) {
    const float* emb = (const float*)d_in[0];    // [1024, 512]
    const float* prox = (const float*)d_in[1];   // [32768, 512]
    const int* labels = (const int*)d_in[2];     // [1024]
    float* out = (float*)d_out;

    char* ws = (char*)d_ws;
    unsigned char* Pq = (unsigned char*)ws;                            // 16 MB
    unsigned char* Aq = Pq + (size_t)C_ROWS * D_DIM;                   // 512 KB
    float* part = (float*)(Aq + (size_t)B_ROWS * D_DIM);               // 1 MB
    float* acc = part + (size_t)NBLK * B_ROWS;
    unsigned* ticket = (unsigned*)(acc + 1);

    norm_rows_kernel<<<(C_ROWS + B_ROWS) / 4, 256, 0, stream>>>(
        prox, emb, Pq, Aq, acc, ticket);
    gemm_lse_kernel<<<dim3(NBLK, B_ROWS / 128), 256, 0, stream>>>(Aq, Pq, part);
    finalize_kernel<<<B_ROWS / 4, 256, 0, stream>>>(
        part, Aq, Pq, labels, acc, ticket, out);
}